// Round 3
// baseline (2101.912 us; speedup 1.0000x reference)
//
#include <hip/hip_runtime.h>
#include <hip/hip_bf16.h>
#include <math.h>

#define NEGF (-1e30f)
#define LOG2E 1.44269504088896340736f
#define LN2 0.69314718055994530942f

typedef short bf16x8 __attribute__((ext_vector_type(8)));
typedef float f32x4 __attribute__((ext_vector_type(4)));

__device__ __forceinline__ unsigned short f2b(float x) {
  __hip_bfloat16 h = __float2bfloat16(x);
  return *reinterpret_cast<unsigned short*>(&h);
}
__device__ __forceinline__ float b2f(unsigned short u) {
  __hip_bfloat16 h;
  *reinterpret_cast<unsigned short*>(&h) = u;
  return __bfloat162float(h);
}
__device__ __forceinline__ float gelu_exact(float x) {
  return 0.5f * x * (1.0f + erff(x * 0.70710678118654752440f));
}

#if __has_builtin(__builtin_amdgcn_exp2f)
__device__ __forceinline__ float fast_exp2(float x) { return __builtin_amdgcn_exp2f(x); }
#else
__device__ __forceinline__ float fast_exp2(float x) { return exp2f(x); }
#endif
#if __has_builtin(__builtin_amdgcn_logf)
__device__ __forceinline__ float fast_log2(float x) { return __builtin_amdgcn_logf(x); }
#else
__device__ __forceinline__ float fast_log2(float x) { return log2f(x); }
#endif

// ---------------------------------------------------------------------------
// fp32 -> bf16 elementwise (vectorized float4 -> 4x bf16)
// ---------------------------------------------------------------------------
__global__ __launch_bounds__(256) void cvt_enc_kernel(
    const float* __restrict__ in, unsigned short* __restrict__ out, long n4)
{
  long i = (long)blockIdx.x * blockDim.x + threadIdx.x;
  const long stride = (long)gridDim.x * blockDim.x;
  for (; i < n4; i += stride) {
    float4 v = ((const float4*)in)[i];
    ushort4 o;
    o.x = f2b(v.x); o.y = f2b(v.y); o.z = f2b(v.z); o.w = f2b(v.w);
    ((ushort4*)out)[i] = o;
  }
}

// ---------------------------------------------------------------------------
// W (K,N) fp32 -> WT (N,K) bf16, 32x32 LDS tile transpose
// ---------------------------------------------------------------------------
__global__ __launch_bounds__(256) void cvt_wt_kernel(
    const float* __restrict__ W, unsigned short* __restrict__ WT, int K, int N)
{
  __shared__ float tile[32][33];
  const int n0 = blockIdx.x * 32, k0 = blockIdx.y * 32;
  const int tx = threadIdx.x, ty = threadIdx.y;  // 32 x 8
#pragma unroll
  for (int i = 0; i < 32; i += 8) {
    int k = k0 + ty + i, n = n0 + tx;
    tile[ty + i][tx] = (k < K && n < N) ? W[(long)k * N + n] : 0.f;
  }
  __syncthreads();
#pragma unroll
  for (int i = 0; i < 32; i += 8) {
    int n = n0 + ty + i, k = k0 + tx;
    if (n < N && k < K) WT[(long)n * K + k] = f2b(tile[tx][ty + i]);
  }
}

// ---------------------------------------------------------------------------
// Unified bf16 MFMA GEMM: out(M,N) = A(M,K) @ WT(N,K)^T + bias [; gelu]
// ---------------------------------------------------------------------------
template<int K, int NT, int EPI>
__global__ __launch_bounds__(512, 4) void gemm_bf16_kernel(
    const unsigned short* __restrict__ A, const unsigned short* __restrict__ WT,
    const float* __restrict__ bias, unsigned short* __restrict__ out, long M)
{
  constexpr int KP = K + 8;
  constexpr int N = NT * 8 * 16;
  extern __shared__ char smem[];
  unsigned short* as = (unsigned short*)smem;  // [32][KP]
  const int tid = threadIdx.x;
  const int lane = tid & 63;
  const int w = tid >> 6;
  const int cl = lane & 15, g = lane >> 4;
  const long row0 = (long)blockIdx.x * 32;
  const int n_base = w * (NT * 16);

  constexpr int CH = 32 * (K / 8);
  for (int c = tid; c < CH; c += 512) {
    int r = c / (K / 8);
    int kc = (c % (K / 8)) * 8;
    long row = row0 + r;
    bf16x8 v = {0, 0, 0, 0, 0, 0, 0, 0};
    if (row < M) v = *(const bf16x8*)&A[row * K + kc];
    *(bf16x8*)&as[r * KP + kc] = v;
  }
  __syncthreads();

  f32x4 acc[2][NT];
#pragma unroll
  for (int mt = 0; mt < 2; ++mt)
#pragma unroll
    for (int nt = 0; nt < NT; ++nt) acc[mt][nt] = (f32x4){0.f, 0.f, 0.f, 0.f};

  const int aoff = cl * KP + g * 8;
  const unsigned short* bptr = WT + (long)(n_base + cl) * K + g * 8;

  for (int kk = 0; kk < K; kk += 32) {
    bf16x8 a0 = *(const bf16x8*)&as[aoff + kk];
    bf16x8 a1 = *(const bf16x8*)&as[aoff + 16 * KP + kk];
    bf16x8 b[NT];
#pragma unroll
    for (int nt = 0; nt < NT; ++nt)
      b[nt] = *(const bf16x8*)&bptr[(long)nt * 16 * K + kk];
#pragma unroll
    for (int nt = 0; nt < NT; ++nt) {
      acc[0][nt] = __builtin_amdgcn_mfma_f32_16x16x32_bf16(a0, b[nt], acc[0][nt], 0, 0, 0);
      acc[1][nt] = __builtin_amdgcn_mfma_f32_16x16x32_bf16(a1, b[nt], acc[1][nt], 0, 0, 0);
    }
  }

  float bv[NT];
#pragma unroll
  for (int nt = 0; nt < NT; ++nt) bv[nt] = bias[n_base + nt * 16 + cl];

  __syncthreads();  // A strip dead; reuse smem as repack buffer [32][N] bf16
  unsigned short* rb = (unsigned short*)smem;
#pragma unroll
  for (int mt = 0; mt < 2; ++mt)
#pragma unroll
    for (int nt = 0; nt < NT; ++nt)
#pragma unroll
      for (int j = 0; j < 4; ++j) {
        float v = acc[mt][nt][j] + bv[nt];
        if (EPI == 1) v = gelu_exact(v);
        rb[(mt * 16 + g * 4 + j) * N + n_base + nt * 16 + cl] = f2b(v);
      }
  __syncthreads();
  constexpr int CH2 = 32 * (N / 8);
  for (int c = tid; c < CH2; c += 512) {
    int r = c / (N / 8);
    long row = row0 + r;
    if (row < M) {
      int nc = (c % (N / 8)) * 8;
      *(bf16x8*)&out[row * N + nc] = *(const bf16x8*)&rb[r * N + nc];
    }
  }
}

// ---------------------------------------------------------------------------
// LayerNorm in place on bf16, one wave per row
// ---------------------------------------------------------------------------
template<int D>
__global__ __launch_bounds__(256) void ln_bf16_kernel(
    unsigned short* __restrict__ X, const float* __restrict__ g,
    const float* __restrict__ bt, long M)
{
  constexpr int NI = D / 256;
  const int lane = threadIdx.x & 63;
  const int wid = threadIdx.x >> 6;
  const long row = (long)blockIdx.x * 4 + wid;
  if (row >= M) return;

  float v[NI * 4];
  float s = 0.f;
#pragma unroll
  for (int i = 0; i < NI; ++i) {
    ushort4 u = *(const ushort4*)&X[row * D + (i * 64 + lane) * 4];
    v[i * 4 + 0] = b2f(u.x); v[i * 4 + 1] = b2f(u.y);
    v[i * 4 + 2] = b2f(u.z); v[i * 4 + 3] = b2f(u.w);
    s += v[i * 4 + 0] + v[i * 4 + 1] + v[i * 4 + 2] + v[i * 4 + 3];
  }
#pragma unroll
  for (int off = 32; off; off >>= 1) s += __shfl_xor(s, off);
  const float mu = s * (1.0f / D);
  float q = 0.f;
#pragma unroll
  for (int i = 0; i < NI * 4; ++i) { float d = v[i] - mu; q += d * d; }
#pragma unroll
  for (int off = 32; off; off >>= 1) q += __shfl_xor(q, off);
  const float rs = rsqrtf(q * (1.0f / D) + 1e-6f);
#pragma unroll
  for (int i = 0; i < NI; ++i) {
    ushort4 o;
    int c = (i * 64 + lane) * 4;
    o.x = f2b((v[i * 4 + 0] - mu) * rs * g[c + 0] + bt[c + 0]);
    o.y = f2b((v[i * 4 + 1] - mu) * rs * g[c + 1] + bt[c + 1]);
    o.z = f2b((v[i * 4 + 2] - mu) * rs * g[c + 2] + bt[c + 2]);
    o.w = f2b((v[i * 4 + 3] - mu) * rs * g[c + 3] + bt[c + 3]);
    *(ushort4*)&X[row * D + c] = o;
  }
}

// ---------------------------------------------------------------------------
// GEMM3 (V=1024) + bias + log_softmax + gather to lp_ext (B,T,S layout,
// pre-scaled by log2(e) for the base-2 CTC scan).
// ---------------------------------------------------------------------------
template<int K>
__global__ __launch_bounds__(512, 4) void gemm3_bf16_kernel(
    const unsigned short* __restrict__ A, const unsigned short* __restrict__ WT,
    const float* __restrict__ bias, const int* __restrict__ targets,
    float* __restrict__ lp_ext, long M, int T, int B, int L, int S)
{
  constexpr int NT = 8, N = 1024, KP = K + 8;
  extern __shared__ char smem[];
  unsigned short* as = (unsigned short*)smem;
  const int tid = threadIdx.x;
  const int lane = tid & 63;
  const int w = tid >> 6;
  const int cl = lane & 15, g = lane >> 4;
  const long row0 = (long)blockIdx.x * 32;
  const int n_base = w * (NT * 16);

  constexpr int CH = 32 * (K / 8);
  for (int c = tid; c < CH; c += 512) {
    int r = c / (K / 8);
    int kc = (c % (K / 8)) * 8;
    long row = row0 + r;
    bf16x8 v = {0, 0, 0, 0, 0, 0, 0, 0};
    if (row < M) v = *(const bf16x8*)&A[row * K + kc];
    *(bf16x8*)&as[r * KP + kc] = v;
  }
  __syncthreads();

  f32x4 acc[2][NT];
#pragma unroll
  for (int mt = 0; mt < 2; ++mt)
#pragma unroll
    for (int nt = 0; nt < NT; ++nt) acc[mt][nt] = (f32x4){0.f, 0.f, 0.f, 0.f};

  const int aoff = cl * KP + g * 8;
  const unsigned short* bptr = WT + (long)(n_base + cl) * K + g * 8;

  for (int kk = 0; kk < K; kk += 32) {
    bf16x8 a0 = *(const bf16x8*)&as[aoff + kk];
    bf16x8 a1 = *(const bf16x8*)&as[aoff + 16 * KP + kk];
    bf16x8 b[NT];
#pragma unroll
    for (int nt = 0; nt < NT; ++nt)
      b[nt] = *(const bf16x8*)&bptr[(long)nt * 16 * K + kk];
#pragma unroll
    for (int nt = 0; nt < NT; ++nt) {
      acc[0][nt] = __builtin_amdgcn_mfma_f32_16x16x32_bf16(a0, b[nt], acc[0][nt], 0, 0, 0);
      acc[1][nt] = __builtin_amdgcn_mfma_f32_16x16x32_bf16(a1, b[nt], acc[1][nt], 0, 0, 0);
    }
  }

#pragma unroll
  for (int nt = 0; nt < NT; ++nt) {
    float bvv = bias[n_base + nt * 16 + cl];
#pragma unroll
    for (int mt = 0; mt < 2; ++mt)
#pragma unroll
      for (int j = 0; j < 4; ++j) acc[mt][nt][j] += bvv;
  }

  __syncthreads();
  float* redbuf = (float*)smem;  // [8][32]

  float rmax[2][4];
#pragma unroll
  for (int mt = 0; mt < 2; ++mt)
#pragma unroll
    for (int j = 0; j < 4; ++j) {
      float m = acc[mt][0][j];
#pragma unroll
      for (int nt = 1; nt < NT; ++nt) m = fmaxf(m, acc[mt][nt][j]);
      rmax[mt][j] = m;
    }
#pragma unroll
  for (int off = 1; off < 16; off <<= 1)
#pragma unroll
    for (int mt = 0; mt < 2; ++mt)
#pragma unroll
      for (int j = 0; j < 4; ++j)
        rmax[mt][j] = fmaxf(rmax[mt][j], __shfl_xor(rmax[mt][j], off));
  if (cl == 0) {
#pragma unroll
    for (int mt = 0; mt < 2; ++mt)
#pragma unroll
      for (int j = 0; j < 4; ++j) redbuf[w * 32 + mt * 16 + g * 4 + j] = rmax[mt][j];
  }
  __syncthreads();
  float rowmax[2][4];
#pragma unroll
  for (int mt = 0; mt < 2; ++mt)
#pragma unroll
    for (int j = 0; j < 4; ++j) {
      float m = redbuf[0 * 32 + mt * 16 + g * 4 + j];
#pragma unroll
      for (int ww = 1; ww < 8; ++ww) m = fmaxf(m, redbuf[ww * 32 + mt * 16 + g * 4 + j]);
      rowmax[mt][j] = m;
    }
  __syncthreads();

  float rsum[2][4];
#pragma unroll
  for (int mt = 0; mt < 2; ++mt)
#pragma unroll
    for (int j = 0; j < 4; ++j) {
      float s = 0.f;
#pragma unroll
      for (int nt = 0; nt < NT; ++nt) s += expf(acc[mt][nt][j] - rowmax[mt][j]);
      rsum[mt][j] = s;
    }
#pragma unroll
  for (int off = 1; off < 16; off <<= 1)
#pragma unroll
    for (int mt = 0; mt < 2; ++mt)
#pragma unroll
      for (int j = 0; j < 4; ++j) rsum[mt][j] += __shfl_xor(rsum[mt][j], off);
  if (cl == 0) {
#pragma unroll
    for (int mt = 0; mt < 2; ++mt)
#pragma unroll
      for (int j = 0; j < 4; ++j) redbuf[w * 32 + mt * 16 + g * 4 + j] = rsum[mt][j];
  }
  __syncthreads();
  float logz[2][4];
#pragma unroll
  for (int mt = 0; mt < 2; ++mt)
#pragma unroll
    for (int j = 0; j < 4; ++j) {
      float s = 0.f;
#pragma unroll
      for (int ww = 0; ww < 8; ++ww) s += redbuf[ww * 32 + mt * 16 + g * 4 + j];
      logz[mt][j] = rowmax[mt][j] + logf(s);
    }

  float* lpbuf = (float*)smem;  // [16][1024] = 64 KB
  for (int h = 0; h < 2; ++h) {
    __syncthreads();
#pragma unroll
    for (int nt = 0; nt < NT; ++nt)
#pragma unroll
      for (int j = 0; j < 4; ++j)
        lpbuf[(g * 4 + j) * 1024 + n_base + nt * 16 + cl] = acc[h][nt][j] - logz[h][j];
    __syncthreads();
    const int tot = 16 * S;
    for (int idx = tid; idx < tot; idx += 512) {
      int r = idx / S;
      int s = idx - r * S;
      long m = row0 + h * 16 + r;
      if (m < M) {
        int bb = (int)(m % B);
        int t = (int)(m / B);
        int lab = (s & 1) ? targets[bb * L + (s >> 1)] : 0;
        lp_ext[((long)bb * T + t) * (long)S + s] = lpbuf[r * 1024 + lab] * LOG2E;
      }
    }
  }
}

// ---------------------------------------------------------------------------
// CTC forward scan, base-2: ONE WAVE per batch element, alpha in registers
// (5 states/lane), neighbor exchange via shfl_up, DEPTH-deep register
// prefetch of the contiguous (B,T,S) lp2 stream. No LDS, no barriers.
// ---------------------------------------------------------------------------
#define CTC_DEPTH 12
__global__ __launch_bounds__(64) void ctc_scan_kernel(
    const float* __restrict__ lp2,  // (B,T,S), log2 units
    const int* __restrict__ targets, const int* __restrict__ inlens,
    const int* __restrict__ tlens, float* __restrict__ partial,
    int T, int B, int L, int S)
{
  const int b = blockIdx.x;
  const int lane = threadIdx.x;
  const int s0 = lane * 5;
  const int inlen = inlens[b];
  const int tlen = tlens[b];
  const int send = 2 * tlen;
  const int capT = inlen - 1;

  bool valid[5], skipj[5];
#pragma unroll
  for (int j = 0; j < 5; ++j) {
    int s = s0 + j;
    valid[j] = (s < S);
    bool sk = false;
    if (valid[j] && (s & 1) && s >= 3) {
      int lab = targets[b * L + (s >> 1)];
      int lab2 = targets[b * L + (s >> 1) - 1];
      sk = (lab != 0) && (lab != lab2);
    }
    skipj[j] = sk;
  }

  const float* lpb = lp2 + (long)b * T * S;

  float a[5];
  float lbv = NEGF, llv = NEGF;
#pragma unroll
  for (int j = 0; j < 5; ++j) {
    int s = s0 + j;
    a[j] = (valid[j] && s <= 1) ? lpb[s] : NEGF;
  }
  if (capT == 0) {
#pragma unroll
    for (int j = 0; j < 5; ++j) {
      int s = s0 + j;
      if (s == send) lbv = a[j];
      if (s == send - 1) llv = a[j];
    }
  }

  float buf[CTC_DEPTH][5];
#pragma unroll
  for (int d = 0; d < CTC_DEPTH; ++d) {
    int t = 1 + d;
    if (t < T) {
      const float* p = lpb + (long)t * S + s0;
#pragma unroll
      for (int j = 0; j < 5; ++j) buf[d][j] = p[j];
    }
  }

  for (int tb = 1; tb < T; tb += CTC_DEPTH) {
#pragma unroll
    for (int d = 0; d < CTC_DEPTH; ++d) {
      int t = tb + d;
      if (t < T) {
        float lp_[5];
#pragma unroll
        for (int j = 0; j < 5; ++j) lp_[j] = buf[d][j];
        int tn = t + CTC_DEPTH;
        if (tn < T) {
          const float* p = lpb + (long)tn * S + s0;
#pragma unroll
          for (int j = 0; j < 5; ++j) buf[d][j] = p[j];
        }
        float o_m1 = __shfl_up(a[4], 1);
        float o_m2 = __shfl_up(a[3], 1);
        if (lane == 0) { o_m1 = NEGF; o_m2 = NEGF; }
        float na[5];
#pragma unroll
        for (int j = 0; j < 5; ++j) {
          float a0 = a[j];
          float a1 = (j >= 1) ? a[j - 1] : o_m1;
          float a2 = skipj[j] ? ((j >= 2) ? a[j - 2] : o_m2) : NEGF;
          float m = fmaxf(fmaxf(a0, a1), a2);
          float sum = fast_exp2(a0 - m) + fast_exp2(a1 - m) + fast_exp2(a2 - m);
          float nv = m + fast_log2(sum) + lp_[j];
          na[j] = valid[j] ? nv : NEGF;
        }
#pragma unroll
        for (int j = 0; j < 5; ++j) a[j] = na[j];
        if (t == capT) {
#pragma unroll
          for (int j = 0; j < 5; ++j) {
            int s = s0 + j;
            if (s == send) lbv = a[j];
            if (s == send - 1) llv = a[j];
          }
        }
      }
    }
  }

#pragma unroll
  for (int off = 32; off; off >>= 1) {
    lbv = fmaxf(lbv, __shfl_xor(lbv, off));
    llv = fmaxf(llv, __shfl_xor(llv, off));
  }
  if (lane == 0) {
    float mx = fmaxf(lbv, llv);
    float l2 = mx + fast_log2(fast_exp2(lbv - mx) + fast_exp2(llv - mx));
    float loss = -LN2 * l2;
    if (!(loss <= 1e29f)) loss = 0.f;  // zero_infinity (also catches NaN)
    partial[b] = loss / (float)tlen;
  }
}

__global__ void reduce_kernel(const float* __restrict__ partial,
                              float* __restrict__ out, int B)
{
  int lane = threadIdx.x;
  float v = (lane < B) ? partial[lane] : 0.f;
#pragma unroll
  for (int off = 32; off; off >>= 1) v += __shfl_xor(v, off);
  if (lane == 0) out[0] = v / (float)B;
}

// ---------------------------------------------------------------------------
extern "C" void kernel_launch(void* const* d_in, const int* in_sizes, int n_in,
                              void* d_out, int out_size, void* d_ws, size_t ws_size,
                              hipStream_t stream) {
  const float* enc = (const float*)d_in[0];
  const float* Wp  = (const float*)d_in[1];
  const float* bp  = (const float*)d_in[2];
  const float* Wt  = (const float*)d_in[3];
  const float* btr = (const float*)d_in[4];
  const float* lng = (const float*)d_in[5];
  const float* lnb = (const float*)d_in[6];
  const float* Wd  = (const float*)d_in[7];
  const float* bd  = (const float*)d_in[8];
  const int* tgt   = (const int*)d_in[9];
  const int* inl   = (const int*)d_in[10];
  const int* tll   = (const int*)d_in[11];

  const int D = in_sizes[2];              // 768
  const int V = in_sizes[8];              // 1024
  const int B = in_sizes[10];             // 32
  const int L = in_sizes[9] / B;          // 150
  const long M = (long)in_sizes[0] / D;   // T*B = 64000
  const int T = (int)(M / B);             // 2000
  const int S = 2 * L + 1;                // 301

  char* wsb = (char*)d_ws;
  size_t off = 0;
  auto alloc = [&](size_t bytes) { char* p = wsb + off; off += (bytes + 255) & ~(size_t)255; return p; };
  unsigned short* encb = (unsigned short*)alloc((size_t)M * D * 2);
  unsigned short* X1b  = (unsigned short*)alloc((size_t)M * D * 2);
  unsigned short* X2b  = (unsigned short*)alloc((size_t)M * D * 2);
  float* LP            = (float*)alloc((size_t)M * S * 4 + 4096);  // slack: lane over-read past S
  unsigned short* WpT  = (unsigned short*)alloc((size_t)D * D * 2);
  unsigned short* WtT  = (unsigned short*)alloc((size_t)D * D * 2);
  unsigned short* WdT  = (unsigned short*)alloc((size_t)D * V * 2);
  float* partial       = (float*)alloc(256);

  cvt_wt_kernel<<<dim3(D / 32, D / 32), dim3(32, 8), 0, stream>>>(Wp, WpT, D, D);
  cvt_wt_kernel<<<dim3(D / 32, D / 32), dim3(32, 8), 0, stream>>>(Wt, WtT, D, D);
  cvt_wt_kernel<<<dim3(V / 32, D / 32), dim3(32, 8), 0, stream>>>(Wd, WdT, D, V);
  cvt_enc_kernel<<<2048, 256, 0, stream>>>(enc, encb, (long)M * D / 4);

  const int grid = (int)((M + 31) / 32);
  const size_t smem12 = (size_t)32 * (768 + 8) * 2;  // 49664
  gemm_bf16_kernel<768, 6, 0><<<grid, 512, smem12, stream>>>(encb, WpT, bp, X1b, M);
  gemm_bf16_kernel<768, 6, 1><<<grid, 512, smem12, stream>>>(X1b, WtT, btr, X2b, M);
  ln_bf16_kernel<768><<<(int)((M + 3) / 4), 256, 0, stream>>>(X2b, lng, lnb, M);
  gemm3_bf16_kernel<768><<<grid, 512, 65536, stream>>>(X2b, WdT, bd, tgt, LP, M, T, B, L, S);

  ctc_scan_kernel<<<B, 64, 0, stream>>>(LP, tgt, inl, tll, partial, T, B, L, S);
  reduce_kernel<<<1, 64, 0, stream>>>(partial, (float*)d_out, B);
}

// Round 4
// 1505.283 us; speedup vs baseline: 1.3964x; 1.3964x over previous
//
#include <hip/hip_runtime.h>
#include <hip/hip_bf16.h>
#include <math.h>

#define NEGF (-1e30f)
#define LOG2E 1.44269504088896340736f
#define LN2 0.69314718055994530942f

typedef short bf16x8 __attribute__((ext_vector_type(8)));
typedef float f32x4 __attribute__((ext_vector_type(4)));

__device__ __forceinline__ unsigned short f2b(float x) {
  __hip_bfloat16 h = __float2bfloat16(x);
  return *reinterpret_cast<unsigned short*>(&h);
}
__device__ __forceinline__ float b2f(unsigned short u) {
  __hip_bfloat16 h;
  *reinterpret_cast<unsigned short*>(&h) = u;
  return __bfloat162float(h);
}
__device__ __forceinline__ float gelu_exact(float x) {
  return 0.5f * x * (1.0f + erff(x * 0.70710678118654752440f));
}

#if __has_builtin(__builtin_amdgcn_exp2f)
__device__ __forceinline__ float fast_exp2(float x) { return __builtin_amdgcn_exp2f(x); }
#else
__device__ __forceinline__ float fast_exp2(float x) { return exp2f(x); }
#endif
#if __has_builtin(__builtin_amdgcn_logf)
__device__ __forceinline__ float fast_log2(float x) { return __builtin_amdgcn_logf(x); }
#else
__device__ __forceinline__ float fast_log2(float x) { return log2f(x); }
#endif

// lp row layout for the CTC scan: 64 lane-groups x 8 floats (5 used, 3 pad)
#define LPROW 512

// ---------------------------------------------------------------------------
// fp32 -> bf16 elementwise
// ---------------------------------------------------------------------------
__global__ __launch_bounds__(256) void cvt_enc_kernel(
    const float* __restrict__ in, unsigned short* __restrict__ out, long n4)
{
  long i = (long)blockIdx.x * blockDim.x + threadIdx.x;
  const long stride = (long)gridDim.x * blockDim.x;
  for (; i < n4; i += stride) {
    float4 v = ((const float4*)in)[i];
    ushort4 o;
    o.x = f2b(v.x); o.y = f2b(v.y); o.z = f2b(v.z); o.w = f2b(v.w);
    ((ushort4*)out)[i] = o;
  }
}

// ---------------------------------------------------------------------------
// W (K,N) fp32 -> WT (N,K) bf16, 32x32 LDS tile transpose
// ---------------------------------------------------------------------------
__global__ __launch_bounds__(256) void cvt_wt_kernel(
    const float* __restrict__ W, unsigned short* __restrict__ WT, int K, int N)
{
  __shared__ float tile[32][33];
  const int n0 = blockIdx.x * 32, k0 = blockIdx.y * 32;
  const int tx = threadIdx.x, ty = threadIdx.y;  // 32 x 8
#pragma unroll
  for (int i = 0; i < 32; i += 8) {
    int k = k0 + ty + i, n = n0 + tx;
    tile[ty + i][tx] = (k < K && n < N) ? W[(long)k * N + n] : 0.f;
  }
  __syncthreads();
#pragma unroll
  for (int i = 0; i < 32; i += 8) {
    int n = n0 + ty + i, k = k0 + tx;
    if (n < N && k < K) WT[(long)n * K + k] = f2b(tile[tx][ty + i]);
  }
}

// ---------------------------------------------------------------------------
// Unified bf16 MFMA GEMM: out(M,N) = A(M,K) @ WT(N,K)^T + bias [; gelu]
// ---------------------------------------------------------------------------
template<int K, int NT, int EPI>
__global__ __launch_bounds__(512, 4) void gemm_bf16_kernel(
    const unsigned short* __restrict__ A, const unsigned short* __restrict__ WT,
    const float* __restrict__ bias, unsigned short* __restrict__ out, long M)
{
  constexpr int KP = K + 8;
  constexpr int N = NT * 8 * 16;
  extern __shared__ char smem[];
  unsigned short* as = (unsigned short*)smem;  // [32][KP]
  const int tid = threadIdx.x;
  const int lane = tid & 63;
  const int w = tid >> 6;
  const int cl = lane & 15, g = lane >> 4;
  const long row0 = (long)blockIdx.x * 32;
  const int n_base = w * (NT * 16);

  constexpr int CH = 32 * (K / 8);
  for (int c = tid; c < CH; c += 512) {
    int r = c / (K / 8);
    int kc = (c % (K / 8)) * 8;
    long row = row0 + r;
    bf16x8 v = {0, 0, 0, 0, 0, 0, 0, 0};
    if (row < M) v = *(const bf16x8*)&A[row * K + kc];
    *(bf16x8*)&as[r * KP + kc] = v;
  }
  __syncthreads();

  f32x4 acc[2][NT];
#pragma unroll
  for (int mt = 0; mt < 2; ++mt)
#pragma unroll
    for (int nt = 0; nt < NT; ++nt) acc[mt][nt] = (f32x4){0.f, 0.f, 0.f, 0.f};

  const int aoff = cl * KP + g * 8;
  const unsigned short* bptr = WT + (long)(n_base + cl) * K + g * 8;

  for (int kk = 0; kk < K; kk += 32) {
    bf16x8 a0 = *(const bf16x8*)&as[aoff + kk];
    bf16x8 a1 = *(const bf16x8*)&as[aoff + 16 * KP + kk];
    bf16x8 b[NT];
#pragma unroll
    for (int nt = 0; nt < NT; ++nt)
      b[nt] = *(const bf16x8*)&bptr[(long)nt * 16 * K + kk];
#pragma unroll
    for (int nt = 0; nt < NT; ++nt) {
      acc[0][nt] = __builtin_amdgcn_mfma_f32_16x16x32_bf16(a0, b[nt], acc[0][nt], 0, 0, 0);
      acc[1][nt] = __builtin_amdgcn_mfma_f32_16x16x32_bf16(a1, b[nt], acc[1][nt], 0, 0, 0);
    }
  }

  float bv[NT];
#pragma unroll
  for (int nt = 0; nt < NT; ++nt) bv[nt] = bias[n_base + nt * 16 + cl];

  __syncthreads();  // A strip dead; reuse smem as repack buffer [32][N] bf16
  unsigned short* rb = (unsigned short*)smem;
#pragma unroll
  for (int mt = 0; mt < 2; ++mt)
#pragma unroll
    for (int nt = 0; nt < NT; ++nt)
#pragma unroll
      for (int j = 0; j < 4; ++j) {
        float v = acc[mt][nt][j] + bv[nt];
        if (EPI == 1) v = gelu_exact(v);
        rb[(mt * 16 + g * 4 + j) * N + n_base + nt * 16 + cl] = f2b(v);
      }
  __syncthreads();
  constexpr int CH2 = 32 * (N / 8);
  for (int c = tid; c < CH2; c += 512) {
    int r = c / (N / 8);
    long row = row0 + r;
    if (row < M) {
      int nc = (c % (N / 8)) * 8;
      *(bf16x8*)&out[row * N + nc] = *(const bf16x8*)&rb[r * N + nc];
    }
  }
}

// ---------------------------------------------------------------------------
// LayerNorm in place on bf16, one wave per row
// ---------------------------------------------------------------------------
template<int D>
__global__ __launch_bounds__(256) void ln_bf16_kernel(
    unsigned short* __restrict__ X, const float* __restrict__ g,
    const float* __restrict__ bt, long M)
{
  constexpr int NI = D / 256;
  const int lane = threadIdx.x & 63;
  const int wid = threadIdx.x >> 6;
  const long row = (long)blockIdx.x * 4 + wid;
  if (row >= M) return;

  float v[NI * 4];
  float s = 0.f;
#pragma unroll
  for (int i = 0; i < NI; ++i) {
    ushort4 u = *(const ushort4*)&X[row * D + (i * 64 + lane) * 4];
    v[i * 4 + 0] = b2f(u.x); v[i * 4 + 1] = b2f(u.y);
    v[i * 4 + 2] = b2f(u.z); v[i * 4 + 3] = b2f(u.w);
    s += v[i * 4 + 0] + v[i * 4 + 1] + v[i * 4 + 2] + v[i * 4 + 3];
  }
#pragma unroll
  for (int off = 32; off; off >>= 1) s += __shfl_xor(s, off);
  const float mu = s * (1.0f / D);
  float q = 0.f;
#pragma unroll
  for (int i = 0; i < NI * 4; ++i) { float d = v[i] - mu; q += d * d; }
#pragma unroll
  for (int off = 32; off; off >>= 1) q += __shfl_xor(q, off);
  const float rs = rsqrtf(q * (1.0f / D) + 1e-6f);
#pragma unroll
  for (int i = 0; i < NI; ++i) {
    ushort4 o;
    int c = (i * 64 + lane) * 4;
    o.x = f2b((v[i * 4 + 0] - mu) * rs * g[c + 0] + bt[c + 0]);
    o.y = f2b((v[i * 4 + 1] - mu) * rs * g[c + 1] + bt[c + 1]);
    o.z = f2b((v[i * 4 + 2] - mu) * rs * g[c + 2] + bt[c + 2]);
    o.w = f2b((v[i * 4 + 3] - mu) * rs * g[c + 3] + bt[c + 3]);
    *(ushort4*)&X[row * D + c] = o;
  }
}

// ---------------------------------------------------------------------------
// GEMM3 (V=1024) + bias + log_softmax + gather to lp_ext.
// lp_ext layout: (B, T, LPROW): state s -> (s/5)*8 + s%5, log2 units.
// ---------------------------------------------------------------------------
template<int K>
__global__ __launch_bounds__(512, 4) void gemm3_bf16_kernel(
    const unsigned short* __restrict__ A, const unsigned short* __restrict__ WT,
    const float* __restrict__ bias, const int* __restrict__ targets,
    float* __restrict__ lp_ext, long M, int T, int B, int L, int S)
{
  constexpr int NT = 8, N = 1024, KP = K + 8;
  extern __shared__ char smem[];
  unsigned short* as = (unsigned short*)smem;
  const int tid = threadIdx.x;
  const int lane = tid & 63;
  const int w = tid >> 6;
  const int cl = lane & 15, g = lane >> 4;
  const long row0 = (long)blockIdx.x * 32;
  const int n_base = w * (NT * 16);

  constexpr int CH = 32 * (K / 8);
  for (int c = tid; c < CH; c += 512) {
    int r = c / (K / 8);
    int kc = (c % (K / 8)) * 8;
    long row = row0 + r;
    bf16x8 v = {0, 0, 0, 0, 0, 0, 0, 0};
    if (row < M) v = *(const bf16x8*)&A[row * K + kc];
    *(bf16x8*)&as[r * KP + kc] = v;
  }
  __syncthreads();

  f32x4 acc[2][NT];
#pragma unroll
  for (int mt = 0; mt < 2; ++mt)
#pragma unroll
    for (int nt = 0; nt < NT; ++nt) acc[mt][nt] = (f32x4){0.f, 0.f, 0.f, 0.f};

  const int aoff = cl * KP + g * 8;
  const unsigned short* bptr = WT + (long)(n_base + cl) * K + g * 8;

  for (int kk = 0; kk < K; kk += 32) {
    bf16x8 a0 = *(const bf16x8*)&as[aoff + kk];
    bf16x8 a1 = *(const bf16x8*)&as[aoff + 16 * KP + kk];
    bf16x8 b[NT];
#pragma unroll
    for (int nt = 0; nt < NT; ++nt)
      b[nt] = *(const bf16x8*)&bptr[(long)nt * 16 * K + kk];
#pragma unroll
    for (int nt = 0; nt < NT; ++nt) {
      acc[0][nt] = __builtin_amdgcn_mfma_f32_16x16x32_bf16(a0, b[nt], acc[0][nt], 0, 0, 0);
      acc[1][nt] = __builtin_amdgcn_mfma_f32_16x16x32_bf16(a1, b[nt], acc[1][nt], 0, 0, 0);
    }
  }

#pragma unroll
  for (int nt = 0; nt < NT; ++nt) {
    float bvv = bias[n_base + nt * 16 + cl];
#pragma unroll
    for (int mt = 0; mt < 2; ++mt)
#pragma unroll
      for (int j = 0; j < 4; ++j) acc[mt][nt][j] += bvv;
  }

  __syncthreads();
  float* redbuf = (float*)smem;  // [8][32]

  float rmax[2][4];
#pragma unroll
  for (int mt = 0; mt < 2; ++mt)
#pragma unroll
    for (int j = 0; j < 4; ++j) {
      float m = acc[mt][0][j];
#pragma unroll
      for (int nt = 1; nt < NT; ++nt) m = fmaxf(m, acc[mt][nt][j]);
      rmax[mt][j] = m;
    }
#pragma unroll
  for (int off = 1; off < 16; off <<= 1)
#pragma unroll
    for (int mt = 0; mt < 2; ++mt)
#pragma unroll
      for (int j = 0; j < 4; ++j)
        rmax[mt][j] = fmaxf(rmax[mt][j], __shfl_xor(rmax[mt][j], off));
  if (cl == 0) {
#pragma unroll
    for (int mt = 0; mt < 2; ++mt)
#pragma unroll
      for (int j = 0; j < 4; ++j) redbuf[w * 32 + mt * 16 + g * 4 + j] = rmax[mt][j];
  }
  __syncthreads();
  float rowmax[2][4];
#pragma unroll
  for (int mt = 0; mt < 2; ++mt)
#pragma unroll
    for (int j = 0; j < 4; ++j) {
      float m = redbuf[0 * 32 + mt * 16 + g * 4 + j];
#pragma unroll
      for (int ww = 1; ww < 8; ++ww) m = fmaxf(m, redbuf[ww * 32 + mt * 16 + g * 4 + j]);
      rowmax[mt][j] = m;
    }
  __syncthreads();

  float rsum[2][4];
#pragma unroll
  for (int mt = 0; mt < 2; ++mt)
#pragma unroll
    for (int j = 0; j < 4; ++j) {
      float s = 0.f;
#pragma unroll
      for (int nt = 0; nt < NT; ++nt) s += expf(acc[mt][nt][j] - rowmax[mt][j]);
      rsum[mt][j] = s;
    }
#pragma unroll
  for (int off = 1; off < 16; off <<= 1)
#pragma unroll
    for (int mt = 0; mt < 2; ++mt)
#pragma unroll
      for (int j = 0; j < 4; ++j) rsum[mt][j] += __shfl_xor(rsum[mt][j], off);
  if (cl == 0) {
#pragma unroll
    for (int mt = 0; mt < 2; ++mt)
#pragma unroll
      for (int j = 0; j < 4; ++j) redbuf[w * 32 + mt * 16 + g * 4 + j] = rsum[mt][j];
  }
  __syncthreads();
  float logz[2][4];
#pragma unroll
  for (int mt = 0; mt < 2; ++mt)
#pragma unroll
    for (int j = 0; j < 4; ++j) {
      float s = 0.f;
#pragma unroll
      for (int ww = 0; ww < 8; ++ww) s += redbuf[ww * 32 + mt * 16 + g * 4 + j];
      logz[mt][j] = rowmax[mt][j] + logf(s);
    }

  float* lpbuf = (float*)smem;  // [16][1024] = 64 KB
  for (int h = 0; h < 2; ++h) {
    __syncthreads();
#pragma unroll
    for (int nt = 0; nt < NT; ++nt)
#pragma unroll
      for (int j = 0; j < 4; ++j)
        lpbuf[(g * 4 + j) * 1024 + n_base + nt * 16 + cl] = acc[h][nt][j] - logz[h][j];
    __syncthreads();
    const int tot = 16 * S;
    for (int idx = tid; idx < tot; idx += 512) {
      int r = idx / S;
      int s = idx - r * S;
      long m = row0 + h * 16 + r;
      if (m < M) {
        int bb = (int)(m % B);
        int t = (int)(m / B);
        int lab = (s & 1) ? targets[bb * L + (s >> 1)] : 0;
        int grp = s / 5, rem = s - grp * 5;
        lp_ext[((long)bb * T + t) * LPROW + grp * 8 + rem] = lpbuf[r * 1024 + lab] * LOG2E;
      }
    }
  }
}

// ---------------------------------------------------------------------------
// CTC forward scan, base-2: ONE WAVE per batch element, alpha in registers
// (5 states/lane), neighbor exchange via shfl_up, CTC_DEPTH-deep register
// prefetch (aligned float4+float per lane via LPROW padding).
// __launch_bounds__(64,1): full VGPR budget -> no scratch spill.
// ---------------------------------------------------------------------------
#define CTC_DEPTH 8
__global__ __launch_bounds__(64, 1) void ctc_scan_kernel(
    const float* __restrict__ lp2,  // (B, T, LPROW), log2 units
    const int* __restrict__ targets, const int* __restrict__ inlens,
    const int* __restrict__ tlens, float* __restrict__ partial,
    int T, int B, int L, int S)
{
  const int b = blockIdx.x;
  const int lane = threadIdx.x;
  const int s0 = lane * 5;
  const int inlen = inlens[b];
  const int tlen = tlens[b];
  const int send = 2 * tlen;
  const int capT = inlen - 1;

  bool valid[5], skipj[5];
#pragma unroll
  for (int j = 0; j < 5; ++j) {
    int s = s0 + j;
    valid[j] = (s < S);
    bool sk = false;
    if (valid[j] && (s & 1) && s >= 3) {
      int lab = targets[b * L + (s >> 1)];
      int lab2 = targets[b * L + (s >> 1) - 1];
      sk = (lab != 0) && (lab != lab2);
    }
    skipj[j] = sk;
  }

  const float* lpb = lp2 + (long)b * T * LPROW + lane * 8;

  float a[5];
  float lbv = NEGF, llv = NEGF;
#pragma unroll
  for (int j = 0; j < 5; ++j) {
    int s = s0 + j;
    a[j] = (valid[j] && s <= 1) ? lpb[j] : NEGF;
  }
  if (capT == 0) {
#pragma unroll
    for (int j = 0; j < 5; ++j) {
      int s = s0 + j;
      if (s == send) lbv = a[j];
      if (s == send - 1) llv = a[j];
    }
  }

  float4 b4[CTC_DEPTH];
  float b1[CTC_DEPTH];

#define CTC_ISSUE(d, t)                                \
  do {                                                 \
    const float* _p = lpb + (long)(t) * LPROW;         \
    b4[d] = *(const float4*)_p;                        \
    b1[d] = _p[4];                                     \
  } while (0)

#define CTC_PROCESS(tcur, d)                                                  \
  do {                                                                        \
    float lp_[5] = {b4[d].x, b4[d].y, b4[d].z, b4[d].w, b1[d]};               \
    float o_m1 = __shfl_up(a[4], 1);                                          \
    float o_m2 = __shfl_up(a[3], 1);                                          \
    if (lane == 0) { o_m1 = NEGF; o_m2 = NEGF; }                              \
    float na[5];                                                              \
    _Pragma("unroll")                                                         \
    for (int j = 0; j < 5; ++j) {                                             \
      float a0 = a[j];                                                        \
      float a1 = (j >= 1) ? a[j - 1] : o_m1;                                  \
      float a2 = skipj[j] ? ((j >= 2) ? a[j - 2] : o_m2) : NEGF;              \
      float m = fmaxf(fmaxf(a0, a1), a2);                                     \
      float sum = fast_exp2(a0 - m) + fast_exp2(a1 - m) + fast_exp2(a2 - m);  \
      float nv = m + fast_log2(sum) + lp_[j];                                 \
      na[j] = valid[j] ? nv : NEGF;                                           \
    }                                                                         \
    _Pragma("unroll")                                                         \
    for (int j = 0; j < 5; ++j) a[j] = na[j];                                 \
    if ((tcur) == capT) {                                                     \
      _Pragma("unroll")                                                       \
      for (int j = 0; j < 5; ++j) {                                           \
        int s = s0 + j;                                                       \
        if (s == send) lbv = a[j];                                            \
        if (s == send - 1) llv = a[j];                                        \
      }                                                                       \
    }                                                                         \
  } while (0)

  // prologue: buffer t = 1 .. CTC_DEPTH
#pragma unroll
  for (int d = 0; d < CTC_DEPTH; ++d) {
    int t = 1 + d;
    if (t < T) CTC_ISSUE(d, t);
  }

  int t = 1;
  for (; t <= T - 2 * CTC_DEPTH; t += CTC_DEPTH) {
#pragma unroll
    for (int d = 0; d < CTC_DEPTH; ++d) {
      CTC_PROCESS(t + d, d);
      CTC_ISSUE(d, t + d + CTC_DEPTH);
    }
  }
#pragma unroll
  for (int d = 0; d < CTC_DEPTH; ++d) {
    int tc = t + d;
    if (tc < T) {
      CTC_PROCESS(tc, d);
      int tn = tc + CTC_DEPTH;
      if (tn < T) CTC_ISSUE(d, tn);
    }
  }
  t += CTC_DEPTH;
#pragma unroll
  for (int d = 0; d < CTC_DEPTH; ++d) {
    int tc = t + d;
    if (tc < T) CTC_PROCESS(tc, d);
  }

#pragma unroll
  for (int off = 32; off; off >>= 1) {
    lbv = fmaxf(lbv, __shfl_xor(lbv, off));
    llv = fmaxf(llv, __shfl_xor(llv, off));
  }
  if (lane == 0) {
    float mx = fmaxf(lbv, llv);
    float l2 = mx + fast_log2(fast_exp2(lbv - mx) + fast_exp2(llv - mx));
    float loss = -LN2 * l2;
    if (!(loss <= 1e29f)) loss = 0.f;  // zero_infinity (also catches NaN)
    partial[b] = loss / (float)tlen;
  }
}

__global__ void reduce_kernel(const float* __restrict__ partial,
                              float* __restrict__ out, int B)
{
  int lane = threadIdx.x;
  float v = (lane < B) ? partial[lane] : 0.f;
#pragma unroll
  for (int off = 32; off; off >>= 1) v += __shfl_xor(v, off);
  if (lane == 0) out[0] = v / (float)B;
}

// ---------------------------------------------------------------------------
extern "C" void kernel_launch(void* const* d_in, const int* in_sizes, int n_in,
                              void* d_out, int out_size, void* d_ws, size_t ws_size,
                              hipStream_t stream) {
  const float* enc = (const float*)d_in[0];
  const float* Wp  = (const float*)d_in[1];
  const float* bp  = (const float*)d_in[2];
  const float* Wt  = (const float*)d_in[3];
  const float* btr = (const float*)d_in[4];
  const float* lng = (const float*)d_in[5];
  const float* lnb = (const float*)d_in[6];
  const float* Wd  = (const float*)d_in[7];
  const float* bd  = (const float*)d_in[8];
  const int* tgt   = (const int*)d_in[9];
  const int* inl   = (const int*)d_in[10];
  const int* tll   = (const int*)d_in[11];

  const int D = in_sizes[2];              // 768
  const int V = in_sizes[8];              // 1024
  const int B = in_sizes[10];             // 32
  const int L = in_sizes[9] / B;          // 150
  const long M = (long)in_sizes[0] / D;   // T*B = 64000
  const int T = (int)(M / B);             // 2000
  const int S = 2 * L + 1;                // 301

  char* wsb = (char*)d_ws;
  size_t off = 0;
  auto alloc = [&](size_t bytes) { char* p = wsb + off; off += (bytes + 255) & ~(size_t)255; return p; };
  unsigned short* encb = (unsigned short*)alloc((size_t)M * D * 2);
  unsigned short* X1b  = (unsigned short*)alloc((size_t)M * D * 2);
  unsigned short* X2b  = encb;  // alias: encb is dead after GEMM1
  float* LP            = (float*)alloc((size_t)B * T * LPROW * 4);
  unsigned short* WpT  = (unsigned short*)alloc((size_t)D * D * 2);
  unsigned short* WtT  = (unsigned short*)alloc((size_t)D * D * 2);
  unsigned short* WdT  = (unsigned short*)alloc((size_t)D * V * 2);
  float* partial       = (float*)alloc(256);

  cvt_wt_kernel<<<dim3(D / 32, D / 32), dim3(32, 8), 0, stream>>>(Wp, WpT, D, D);
  cvt_wt_kernel<<<dim3(D / 32, D / 32), dim3(32, 8), 0, stream>>>(Wt, WtT, D, D);
  cvt_wt_kernel<<<dim3(V / 32, D / 32), dim3(32, 8), 0, stream>>>(Wd, WdT, D, V);
  cvt_enc_kernel<<<2048, 256, 0, stream>>>(enc, encb, (long)M * D / 4);

  const int grid = (int)((M + 31) / 32);
  const size_t smem12 = (size_t)32 * (768 + 8) * 2;  // 49664
  gemm_bf16_kernel<768, 6, 0><<<grid, 512, smem12, stream>>>(encb, WpT, bp, X1b, M);
  gemm_bf16_kernel<768, 6, 1><<<grid, 512, smem12, stream>>>(X1b, WtT, btr, X2b, M);
  ln_bf16_kernel<768><<<(int)((M + 3) / 4), 256, 0, stream>>>(X2b, lng, lnb, M);
  gemm3_bf16_kernel<768><<<grid, 512, 65536, stream>>>(X2b, WdT, bd, tgt, LP, M, T, B, L, S);

  ctc_scan_kernel<<<B, 64, 0, stream>>>(LP, tgt, inl, tll, partial, T, B, L, S);
  reduce_kernel<<<1, 64, 0, stream>>>(partial, (float*)d_out, B);
}